// Round 1
// baseline (1234.885 us; speedup 1.0000x reference)
//
#include <hip/hip_runtime.h>

// VQ quantizer forward (eval): nearest codebook entry per spatial vector,
// quantized output in (b,c,h,w) layout, plus commitment loss scalar.
//
// Shapes: x (16,256,64,64) fp32, weight (2048,256) fp32.
// d_out = 16,777,216 floats (quantized) + 1 float (latent_loss).

constexpr int NE   = 2048;      // n_embed
constexpr int DIM  = 256;       // embed_dim
constexpr int HW   = 4096;      // 64*64
constexpr int NTOT = 16777216;  // 16*256*64*64
constexpr float LOSS_SCALE = 0.25f / 16777216.0f;  // commitment_cost / numel

// Kernel 1: per-code squared norms; also zero the loss accumulator slot
// (d_out is re-poisoned to 0xAA before every timed launch).
__global__ __launch_bounds__(256) void w2_kernel(const float* __restrict__ w,
                                                 float* __restrict__ w2,
                                                 float* __restrict__ loss_slot) {
    const int lane = threadIdx.x & 63;
    const int wv   = threadIdx.x >> 6;
    const int code = blockIdx.x * 4 + wv;   // one wave per code
    float4 v = *reinterpret_cast<const float4*>(w + (size_t)code * DIM + lane * 4);
    float s = v.x * v.x + v.y * v.y + v.z * v.z + v.w * v.w;
#pragma unroll
    for (int off = 32; off > 0; off >>= 1) s += __shfl_down(s, off, 64);
    if (lane == 0) w2[code] = s;
    if (blockIdx.x == 0 && threadIdx.x == 0) *loss_slot = 0.0f;
}

// Kernel 2: 32 spatial positions per block, full 2048-code argmin fused with
// the distance GEMM; epilogue writes gathered codewords + loss partial.
__global__ __launch_bounds__(256) void vq_kernel(const float* __restrict__ x,
                                                 const float* __restrict__ w,
                                                 const float* __restrict__ w2,
                                                 float* __restrict__ out,
                                                 float* __restrict__ loss_slot) {
    // stride 260: keeps 16B alignment for float4; with pos = (tid&7)+8p the
    // 8 distinct ds_read_b128 addresses per instruction cover all 32 banks.
    __shared__ float xs[32][260];
    __shared__ float red_d[32][33];
    __shared__ int   red_i[32][33];
    __shared__ int   best_code[32];
    __shared__ float wave_sum[4];

    const int tid = threadIdx.x;
    const int blk = blockIdx.x;
    const int b   = blk >> 7;            // 128 blocks per image (4096/32)
    const int hw0 = (blk & 127) << 5;
    const size_t base = (size_t)b * (DIM * HW) + hw0;

    // Stage x tile transposed: xs[i][c] = x[b, c, hw0 + i]. Coalesced:
    // 32 consecutive lanes read 32 consecutive floats of one channel row.
    for (int it = 0; it < 32; ++it) {
        int l = it * 256 + tid;
        int c = l >> 5, i = l & 31;
        xs[i][c] = x[base + (size_t)c * HW + i];
    }
    __syncthreads();

    const int pos_t  = tid & 7;   // 8 position groups
    const int code_t = tid >> 3;  // 32 code groups

    float bestd[4] = {3.4e38f, 3.4e38f, 3.4e38f, 3.4e38f};
    int   besti[4] = {0, 0, 0, 0};

    for (int chunk = 0; chunk < NE; chunk += 256) {
        const int e0 = chunk + code_t * 8;   // this thread's 8 codes (ascending)
        float acc[4][8];
#pragma unroll
        for (int p = 0; p < 4; ++p)
#pragma unroll
            for (int j = 0; j < 8; ++j) acc[p][j] = 0.0f;

        for (int c = 0; c < DIM; c += 4) {
            float4 xv[4];
#pragma unroll
            for (int p = 0; p < 4; ++p)
                xv[p] = *reinterpret_cast<const float4*>(&xs[pos_t + 8 * p][c]);
#pragma unroll
            for (int j = 0; j < 8; ++j) {
                float4 wv = *reinterpret_cast<const float4*>(w + (size_t)(e0 + j) * DIM + c);
#pragma unroll
                for (int p = 0; p < 4; ++p) {
                    acc[p][j] = fmaf(xv[p].x, wv.x, acc[p][j]);
                    acc[p][j] = fmaf(xv[p].y, wv.y, acc[p][j]);
                    acc[p][j] = fmaf(xv[p].z, wv.z, acc[p][j]);
                    acc[p][j] = fmaf(xv[p].w, wv.w, acc[p][j]);
                }
            }
        }
        // distance = ||w||^2 - 2 x.w  (|| x ||^2 is row-constant, argmin-invariant)
#pragma unroll
        for (int j = 0; j < 8; ++j) {
            const float bias = w2[e0 + j];
#pragma unroll
            for (int p = 0; p < 4; ++p) {
                float d = fmaf(-2.0f, acc[p][j], bias);
                if (d < bestd[p]) { bestd[p] = d; besti[p] = e0 + j; }  // strict < keeps lowest idx
            }
        }
    }

    // Cross-thread argmin reduction per position (tie-break: lowest index,
    // matching jnp.argmin first-occurrence semantics).
#pragma unroll
    for (int p = 0; p < 4; ++p) {
        int pos = pos_t + 8 * p;
        red_d[pos][code_t] = bestd[p];
        red_i[pos][code_t] = besti[p];
    }
    __syncthreads();

    if (tid < 32) {
        float bd = red_d[tid][0];
        int   bi = red_i[tid][0];
        for (int k = 1; k < 32; ++k) {
            float d = red_d[tid][k];
            int   i = red_i[tid][k];
            if (d < bd || (d == bd && i < bi)) { bd = d; bi = i; }
        }
        best_code[tid] = bi;
    }
    __syncthreads();

    // Epilogue: out[b, c, hw0+i] = w[best[i]][c]; accumulate (q - x)^2.
    float lsum = 0.0f;
    for (int it = 0; it < 32; ++it) {
        int l = it * 256 + tid;
        int c = l >> 5, i = l & 31;
        float wv = w[(size_t)best_code[i] * DIM + c];
        out[base + (size_t)c * HW + i] = wv;
        float dlt = wv - xs[i][c];
        lsum = fmaf(dlt, dlt, lsum);
    }

#pragma unroll
    for (int off = 32; off > 0; off >>= 1) lsum += __shfl_down(lsum, off, 64);
    if ((tid & 63) == 0) wave_sum[tid >> 6] = lsum;
    __syncthreads();
    if (tid == 0)
        atomicAdd(loss_slot,
                  (wave_sum[0] + wave_sum[1] + wave_sum[2] + wave_sum[3]) * LOSS_SCALE);
}

extern "C" void kernel_launch(void* const* d_in, const int* in_sizes, int n_in,
                              void* d_out, int out_size, void* d_ws, size_t ws_size,
                              hipStream_t stream) {
    const float* x = (const float*)d_in[0];      // 16*256*64*64 fp32
    const float* w = (const float*)d_in[1];      // 2048*256 fp32
    float* out       = (float*)d_out;            // quantized (NTOT) + loss (1)
    float* loss_slot = out + NTOT;
    float* w2        = (float*)d_ws;             // 2048 floats scratch

    w2_kernel<<<NE / 4, 256, 0, stream>>>(w, w2, loss_slot);
    vq_kernel<<<65536 / 32, 256, 0, stream>>>(x, w, w2, out, loss_slot);
}

// Round 2
// 440.077 us; speedup vs baseline: 2.8061x; 2.8061x over previous
//
#include <hip/hip_runtime.h>

// VQ quantizer forward via bf16 MFMA distance GEMM + exact fp32 candidate
// refinement. x (16,256,64,64) fp32, w (2048,256) fp32.
// d_out = 16,777,216 floats (quantized, (b,c,h,w)) + 1 float (latent loss).

typedef __attribute__((ext_vector_type(8))) short short8;  // 8 bf16 (4 VGPR)
typedef __attribute__((ext_vector_type(4))) float f32x4;   // MFMA C/D

constexpr int NE  = 2048;
constexpr int DIM = 256;
constexpr int HW  = 4096;
constexpr int NTOT = 16777216;
constexpr int ROWS = 32;        // spatial positions per block
constexpr int NT   = 2;         // 16-row MFMA n-tiles
constexpr int CAP  = 32;        // candidate list capacity per row
constexpr int SCAP = 8;         // survivors refined per row
constexpr float TAU   = 0.75f;  // collection window (bf16 err sigma~0.05)
constexpr float SLACK = 6.0f;   // prune window (covers bf16 storage rounding)
constexpr float LOSS_SCALE = 0.25f / 16777216.0f;

__device__ __forceinline__ unsigned short f2bf(float f) {  // RNE fp32->bf16
    unsigned u = __builtin_bit_cast(unsigned, f);
    u += 0x7fffu + ((u >> 16) & 1u);
    return (unsigned short)(u >> 16);
}
__device__ __forceinline__ float bf2f(unsigned short b) {
    unsigned u = ((unsigned)b) << 16;
    return __builtin_bit_cast(float, u);
}
// monotone float<->uint keys so LDS atomicMin works on distances (can be <0)
__device__ __forceinline__ unsigned fkey(float f) {
    unsigned u = __builtin_bit_cast(unsigned, f);
    return u ^ ((unsigned)((int)u >> 31) | 0x80000000u);
}
__device__ __forceinline__ float funkey(unsigned k) {
    unsigned u = (k & 0x80000000u) ? (k & 0x7fffffffu) : ~k;
    return __builtin_bit_cast(float, u);
}

// Kernel 1: per-code ||w||^2 (fp32) + bf16 copy of w; zero the loss slot.
__global__ __launch_bounds__(256) void prep_kernel(const float* __restrict__ w,
                                                   unsigned short* __restrict__ wbf,
                                                   float* __restrict__ w2,
                                                   float* __restrict__ loss_slot) {
    const int lane = threadIdx.x & 63;
    const int wv   = threadIdx.x >> 6;
    const int code = blockIdx.x * 4 + wv;   // one wave per code
    float4 v = *reinterpret_cast<const float4*>(w + (size_t)code * DIM + lane * 4);
    float s = v.x * v.x + v.y * v.y + v.z * v.z + v.w * v.w;
#pragma unroll
    for (int off = 32; off > 0; off >>= 1) s += __shfl_down(s, off, 64);
    if (lane == 0) w2[code] = s;
    ushort4 u4;
    u4.x = f2bf(v.x); u4.y = f2bf(v.y); u4.z = f2bf(v.z); u4.w = f2bf(v.w);
    *reinterpret_cast<ushort4*>(wbf + (size_t)code * DIM + lane * 4) = u4;
    if (blockIdx.x == 0 && threadIdx.x == 0) *loss_slot = 0.0f;
}

__global__ __launch_bounds__(256, 3) void vq_kernel(const float* __restrict__ x,
                                                    const float* __restrict__ w,
                                                    const unsigned short* __restrict__ wbf,
                                                    const float* __restrict__ w2g,
                                                    float* __restrict__ out,
                                                    float* __restrict__ loss_slot) {
    __shared__ float    xs[ROWS * 257];   // fp32 x tile, odd stride: conflict-free
    __shared__ unsigned cand[ROWS * CAP]; // (code<<16)|bf16(d)
    __shared__ unsigned cnt[ROWS];
    __shared__ unsigned runmin[ROWS];     // fkey of running bf16-min distance
    __shared__ int      scnt[ROWS];
    __shared__ int      bestc[ROWS];
    __shared__ float    wave_sum[4];

    const int tid = threadIdx.x;
    const int blk = blockIdx.x;
    const int b   = blk >> 7;             // 128 blocks per image (4096/32)
    const int hw0 = (blk & 127) << 5;
    const size_t base = (size_t)b * (DIM * HW) + hw0;

    // ---- stage x tile (transposed): xs[i][c] = x[b, c, hw0+i] ----
#pragma unroll
    for (int it = 0; it < 8; ++it) {
        int l  = it * 256 + tid;          // 2048 float4 loads
        int c  = l >> 3;
        int i4 = (l & 7) << 2;
        float4 v = *reinterpret_cast<const float4*>(x + base + (size_t)c * HW + i4);
        xs[(i4 + 0) * 257 + c] = v.x;
        xs[(i4 + 1) * 257 + c] = v.y;
        xs[(i4 + 2) * 257 + c] = v.z;
        xs[(i4 + 3) * 257 + c] = v.w;
    }
    if (tid < ROWS) { cnt[tid] = 0u; runmin[tid] = fkey(1e38f); }
    __syncthreads();

    const int wave = tid >> 6;
    const int lane = tid & 63;
    const int col  = lane & 15;           // spatial row within n-tile
    const int quad = lane >> 4;

    // ---- x B-fragments, register-resident: B[k=quad*8+j][n=col] ----
    short8 bx[NT][8];
#pragma unroll
    for (int nt = 0; nt < NT; ++nt) {
        const float* xr = xs + (nt * 16 + col) * 257 + quad * 8;
#pragma unroll
        for (int kk = 0; kk < 8; ++kk) {
            short8 f;
#pragma unroll
            for (int j = 0; j < 8; ++j) f[j] = (short)f2bf(xr[kk * 32 + j]);
            bx[nt][kk] = f;
        }
    }

    const int cb0 = wave * 512;           // this wave's code slice

    // ---- seed pass (m-tile 0): prime runmin so collection stays sparse ----
    {
        const short8* wp = reinterpret_cast<const short8*>(wbf + (size_t)(cb0 + col) * DIM);
        short8 aw[8];
#pragma unroll
        for (int kk = 0; kk < 8; ++kk) aw[kk] = wp[kk * 4 + quad];
        f32x4 acc[NT];
#pragma unroll
        for (int nt = 0; nt < NT; ++nt) acc[nt] = (f32x4){0.f, 0.f, 0.f, 0.f};
#pragma unroll
        for (int kk = 0; kk < 8; ++kk)
#pragma unroll
            for (int nt = 0; nt < NT; ++nt)
                acc[nt] = __builtin_amdgcn_mfma_f32_16x16x32_bf16(aw[kk], bx[nt][kk], acc[nt], 0, 0, 0);
        float4 w2v = *reinterpret_cast<const float4*>(w2g + cb0 + quad * 4);
        float w2a[4] = {w2v.x, w2v.y, w2v.z, w2v.w};
#pragma unroll
        for (int nt = 0; nt < NT; ++nt) {
            float local = 1e38f;
#pragma unroll
            for (int j = 0; j < 4; ++j)
                local = fminf(local, fmaf(-2.f, acc[nt][j], w2a[j]));
            atomicMin(&runmin[nt * 16 + col], fkey(local));
        }
    }
    __syncthreads();

    // ---- main pass: distances + candidate collection ----
    for (int mt = 0; mt < 32; ++mt) {
        const int cb = cb0 + mt * 16;
        float cmin[NT];
#pragma unroll
        for (int nt = 0; nt < NT; ++nt) cmin[nt] = funkey(runmin[nt * 16 + col]);

        // A-frags: w bf16 straight from global (L2-resident), 16B/lane
        const short8* wp = reinterpret_cast<const short8*>(wbf + (size_t)(cb + col) * DIM);
        short8 aw[8];
#pragma unroll
        for (int kk = 0; kk < 8; ++kk) aw[kk] = wp[kk * 4 + quad];

        f32x4 acc[NT];
#pragma unroll
        for (int nt = 0; nt < NT; ++nt) acc[nt] = (f32x4){0.f, 0.f, 0.f, 0.f};
#pragma unroll
        for (int kk = 0; kk < 8; ++kk)
#pragma unroll
            for (int nt = 0; nt < NT; ++nt)
                acc[nt] = __builtin_amdgcn_mfma_f32_16x16x32_bf16(aw[kk], bx[nt][kk], acc[nt], 0, 0, 0);

        float4 w2v = *reinterpret_cast<const float4*>(w2g + cb + quad * 4);
        float w2a[4] = {w2v.x, w2v.y, w2v.z, w2v.w};
#pragma unroll
        for (int nt = 0; nt < NT; ++nt) {
            const int row = nt * 16 + col;
#pragma unroll
            for (int j = 0; j < 4; ++j) {
                const int code = cb + quad * 4 + j;
                float d = fmaf(-2.f, acc[nt][j], w2a[j]);
                if (d < cmin[nt] + TAU) {      // rare: records + tau-window
                    unsigned slot = atomicAdd(&cnt[row], 1u);
                    if (slot < (unsigned)CAP)
                        cand[row * CAP + slot] = ((unsigned)code << 16) | (unsigned)f2bf(d);
                    if (d < cmin[nt]) {
                        cmin[nt] = d;
                        atomicMin(&runmin[row], fkey(d));
                    }
                }
            }
        }
    }
    __syncthreads();

    // ---- survivor selection: keep <=SCAP smallest bf16-d within SLACK ----
    if (tid < ROWS) {
        int n = (int)min(cnt[tid], (unsigned)CAP);
        float thr = funkey(runmin[tid]) + SLACK;
        float dls[SCAP]; int cls[SCAP]; int s = 0;
        for (int t = 0; t < n; ++t) {
            unsigned e = cand[tid * CAP + t];
            float d  = bf2f((unsigned short)(e & 0xffffu));
            int code = (int)(e >> 16);
            if (d > thr) continue;
            if (s == SCAP) {
                if (d > dls[SCAP - 1] || (d == dls[SCAP - 1] && code > cls[SCAP - 1])) continue;
                s = SCAP - 1;
            }
            int p = s;
            while (p > 0 && (d < dls[p - 1] || (d == dls[p - 1] && code < cls[p - 1]))) {
                dls[p] = dls[p - 1]; cls[p] = cls[p - 1]; --p;
            }
            dls[p] = d; cls[p] = code; ++s;
        }
        scnt[tid] = s;
        for (int t = 0; t < s; ++t) cand[tid * CAP + t] = (unsigned)cls[t];
    }
    __syncthreads();

    // ---- exact fp32 refinement (one wave per row, ~1-2 dots/row avg) ----
    for (int r = wave; r < ROWS; r += 4) {
        const int s = scnt[r];
        float bd = 1e38f; int bc = 0;
        for (int t = 0; t < s; ++t) {
            const int code = (int)cand[r * CAP + t];
            float4 wv = *reinterpret_cast<const float4*>(w + (size_t)code * DIM + lane * 4);
            const float* xr = xs + r * 257 + lane * 4;
            float sum = xr[0] * wv.x + xr[1] * wv.y + xr[2] * wv.z + xr[3] * wv.w;
#pragma unroll
            for (int o = 1; o < 64; o <<= 1) sum += __shfl_xor(sum, o, 64);
            float d = w2g[code] - 2.0f * sum;
            if (t == 0 || d < bd || (d == bd && code < bc)) { bd = d; bc = code; }
        }
        if (lane == 0) bestc[r] = bc;
    }
    __syncthreads();

    // ---- epilogue: gather codewords, write out, commitment loss ----
    float lsum = 0.f;
#pragma unroll 4
    for (int it = 0; it < 32; ++it) {
        int l = it * 256 + tid;
        int c = l >> 5, i = l & 31;
        float wv = w[(size_t)bestc[i] * DIM + c];
        out[base + (size_t)c * HW + i] = wv;
        float dlt = wv - xs[i * 257 + c];
        lsum = fmaf(dlt, dlt, lsum);
    }
#pragma unroll
    for (int off = 32; off > 0; off >>= 1) lsum += __shfl_down(lsum, off, 64);
    if (lane == 0) wave_sum[wave] = lsum;
    __syncthreads();
    if (tid == 0)
        atomicAdd(loss_slot,
                  (wave_sum[0] + wave_sum[1] + wave_sum[2] + wave_sum[3]) * LOSS_SCALE);
}

extern "C" void kernel_launch(void* const* d_in, const int* in_sizes, int n_in,
                              void* d_out, int out_size, void* d_ws, size_t ws_size,
                              hipStream_t stream) {
    const float* x = (const float*)d_in[0];
    const float* w = (const float*)d_in[1];
    float* out       = (float*)d_out;
    float* loss_slot = out + NTOT;
    unsigned short* wbf = (unsigned short*)d_ws;                       // 1 MB bf16 w
    float* w2 = (float*)((char*)d_ws + (size_t)NE * DIM * sizeof(unsigned short));

    prep_kernel<<<NE / 4, 256, 0, stream>>>(w, wbf, w2, loss_slot);
    vq_kernel<<<65536 / ROWS, 256, 0, stream>>>(x, w, wbf, w2, out, loss_slot);
}

// Round 3
// 310.974 us; speedup vs baseline: 3.9710x; 1.4152x over previous
//
#include <hip/hip_runtime.h>

// VQ quantizer forward: LDS-staged bf16-MFMA distance GEMM + exact fp32
// candidate refinement. x (16,256,64,64) fp32, w (2048,256) fp32.
// d_out = 16,777,216 floats (quantized, (b,c,h,w)) + 1 float (latent loss).

typedef __attribute__((ext_vector_type(8))) short short8;  // 8 bf16 (4 VGPR)
typedef __attribute__((ext_vector_type(4))) float f32x4;   // MFMA C/D

#define GLOBAL_AS __attribute__((address_space(1)))
#define LOCAL_AS  __attribute__((address_space(3)))

constexpr int NE   = 2048;
constexpr int DIM  = 256;
constexpr int HW   = 4096;
constexpr int NTOT = 16777216;
constexpr int ROWS   = 64;      // spatial rows per block
constexpr int CHUNK  = 64;      // codes staged per iteration (32 KB)
constexpr int NCHUNK = NE / CHUNK;
constexpr int CAP    = 32;      // candidate list capacity per row
constexpr float TAU   = 0.75f;  // collect window (bf16-MFMA err ~17 sigma)
constexpr float SLACK = 1.0f;   // ambiguity window triggering fp32 refine
constexpr float LOSS_SCALE = 0.25f / 16777216.0f;

__device__ __forceinline__ unsigned short f2bf(float f) {  // RNE fp32->bf16
    unsigned u = __builtin_bit_cast(unsigned, f);
    u += 0x7fffu + ((u >> 16) & 1u);
    return (unsigned short)(u >> 16);
}
// monotone float<->uint keys (works for negative distances too)
__device__ __forceinline__ unsigned fkey(float f) {
    unsigned u = __builtin_bit_cast(unsigned, f);
    return u ^ ((unsigned)((int)u >> 31) | 0x80000000u);
}
__device__ __forceinline__ float funkey(unsigned k) {
    unsigned u = (k & 0x80000000u) ? (k & 0x7fffffffu) : ~k;
    return __builtin_bit_cast(float, u);
}
// packed candidate/runmin entry: truncated fkey (21 bits kept) | code (11 bits)
__device__ __forceinline__ unsigned pack_dc(float d, int code) {
    return (fkey(d) & 0xFFFFF800u) | (unsigned)code;
}

// Kernel 1: ||w||^2 + SWIZZLED bf16 copy of w (16B units permuted so the
// vq kernel's ds_read_b128 A-fragments spread uniformly over bank groups);
// also zero the loss slot (d_out re-poisoned to 0xAA each launch).
__global__ __launch_bounds__(256) void prep_kernel(const float* __restrict__ w,
                                                   unsigned short* __restrict__ wbf,
                                                   float* __restrict__ w2,
                                                   float* __restrict__ loss_slot) {
    const int lane = threadIdx.x & 63;
    const int wv   = threadIdx.x >> 6;
    const int code = blockIdx.x * 4 + wv;   // one wave per code row
    float4 v = *reinterpret_cast<const float4*>(w + (size_t)code * DIM + lane * 4);
    float s = v.x * v.x + v.y * v.y + v.z * v.z + v.w * v.w;
#pragma unroll
    for (int off = 32; off > 0; off >>= 1) s += __shfl_down(s, off, 64);
    if (lane == 0) w2[code] = s;
    // lane covers k = 4*lane..4*lane+3 -> 16B unit u = lane>>1, half = lane&1
    const int u  = lane >> 1;
    const int p  = (u & 24) | ((u + (code & 15)) & 7);   // swizzled unit pos
    ushort4 u4;
    u4.x = f2bf(v.x); u4.y = f2bf(v.y); u4.z = f2bf(v.z); u4.w = f2bf(v.w);
    *reinterpret_cast<ushort4*>(wbf + (size_t)code * DIM + p * 8 + (lane & 1) * 4) = u4;
    if (blockIdx.x == 0 && threadIdx.x == 0) *loss_slot = 0.0f;
}

__global__ __launch_bounds__(256, 2) void vq_kernel(const float* __restrict__ x,
                                                    const float* __restrict__ wg,
                                                    const unsigned short* __restrict__ wbf,
                                                    const float* __restrict__ w2g,
                                                    float* __restrict__ out,
                                                    float* __restrict__ loss_slot) {
    // ubuf reused: phase1 x-transpose [32][260] f32 / main-loop w chunk 32KB /
    // epilogue codeword staging [16][260] f32
    __shared__ alignas(16) unsigned char ubuf[33280];
    __shared__ unsigned runmin[ROWS];     // packed (trunc fkey | code), atomicMin
    __shared__ unsigned cand[ROWS * CAP]; // packed entries
    __shared__ unsigned cnt[ROWS];
    __shared__ float    dbest[ROWS];
    __shared__ int      bestc[ROWS];
    __shared__ int      scnt[ROWS];
    __shared__ float    xn2[ROWS];        // per-row ||x||^2 (fp32 exact)

    const int tid = threadIdx.x;
    const int blk = blockIdx.x;
    const int b   = blk >> 6;             // 64 blocks per image (4096/64)
    const int hw0 = (blk & 63) << 6;
    const size_t base = (size_t)b * (DIM * HW) + hw0;

    const int wv   = tid >> 6;
    const int lane = tid & 63;
    const int col  = lane & 15;
    const int quad = lane >> 4;

    if (tid < ROWS) { runmin[tid] = 0xFFFFFFFFu; cnt[tid] = 0u; xn2[tid] = 0.f; }

    // ---- phase 1: stage x (2 passes of 32 rows), build register B-frags ----
    float* xst = (float*)ubuf;            // [32][260]
    short8 bx[4][8];                      // B[k=kk*32+quad*8+j][n=nt*16+col]
    const int irow = tid & 31;
    const int cgrp = tid >> 5;
    for (int p = 0; p < 2; ++p) {
        __syncthreads();
        float myxn2 = 0.f;
        for (int it = 0; it < 32; ++it) {
            int c = it * 8 + cgrp;
            float v = x[base + (size_t)c * HW + p * 32 + irow];
            xst[irow * 260 + c] = v;
            myxn2 = fmaf(v, v, myxn2);
        }
        atomicAdd(&xn2[p * 32 + irow], myxn2);
        __syncthreads();
#pragma unroll
        for (int t = 0; t < 2; ++t) {
            const int nt = 2 * p + t;
            const float* xr = xst + (t * 16 + col) * 260 + quad * 8;
#pragma unroll
            for (int kk = 0; kk < 8; ++kk) {
                float4 a = *reinterpret_cast<const float4*>(xr + kk * 32);
                float4 c4 = *reinterpret_cast<const float4*>(xr + kk * 32 + 4);
                short8 f;
                f[0] = (short)f2bf(a.x);  f[1] = (short)f2bf(a.y);
                f[2] = (short)f2bf(a.z);  f[3] = (short)f2bf(a.w);
                f[4] = (short)f2bf(c4.x); f[5] = (short)f2bf(c4.y);
                f[6] = (short)f2bf(c4.z); f[7] = (short)f2bf(c4.w);
                bx[nt][kk] = f;
            }
        }
    }

    // ---- main loop: stage 64-code chunk -> MFMA -> collect ----
    unsigned short* wch = (unsigned short*)ubuf;   // swizzled chunk, 32 KB
    const int clocal = wv * 16 + col;              // this lane's A-row in chunk
    for (int ch = 0; ch < NCHUNK; ++ch) {
        const int cb = ch * CHUNK;
        __syncthreads();                           // prev readers done with ubuf
#pragma unroll
        for (int it = 0; it < 8; ++it) {           // 32KB via DMA, 16B/lane
            const unsigned short* g = wbf + (size_t)cb * DIM + it * 2048 + wv * 512 + lane * 8;
            __builtin_amdgcn_global_load_lds((const GLOBAL_AS unsigned int*)g,
                                             (LOCAL_AS unsigned int*)(wch + it * 2048 + wv * 512),
                                             16, 0, 0);
        }
        __syncthreads();                           // vmcnt drain -> chunk ready

        short8 aw[8];                              // A[m=clocal][k=kk*32+quad*8+j]
#pragma unroll
        for (int kk = 0; kk < 8; ++kk) {
            const int u = kk * 4 + quad;
            const int p = (u & 24) | ((u + col) & 7);
            aw[kk] = *reinterpret_cast<const short8*>(wch + clocal * DIM + p * 8);
        }
        f32x4 acc[4];
#pragma unroll
        for (int nt = 0; nt < 4; ++nt) acc[nt] = (f32x4){0.f, 0.f, 0.f, 0.f};
#pragma unroll
        for (int kk = 0; kk < 8; ++kk)
#pragma unroll
            for (int nt = 0; nt < 4; ++nt)
                acc[nt] = __builtin_amdgcn_mfma_f32_16x16x32_bf16(aw[kk], bx[nt][kk], acc[nt], 0, 0, 0);

        float4 w2v = *reinterpret_cast<const float4*>(w2g + cb + wv * 16 + quad * 4);
        const float w2a[4] = {w2v.x, w2v.y, w2v.z, w2v.w};
        float dd[4][4];
#pragma unroll
        for (int nt = 0; nt < 4; ++nt)
#pragma unroll
            for (int j = 0; j < 4; ++j)
                dd[nt][j] = fmaf(-2.f, acc[nt][j], w2a[j]);

        // seed runmin: per-row min over this wave's 16 codes (shuffle x-quad)
#pragma unroll
        for (int nt = 0; nt < 4; ++nt) {
            float ld = dd[nt][0]; int lj = 0;
#pragma unroll
            for (int j = 1; j < 4; ++j) if (dd[nt][j] < ld) { ld = dd[nt][j]; lj = j; }
            int lc = cb + wv * 16 + quad * 4 + lj;
#pragma unroll
            for (int m = 16; m < 64; m <<= 1) {
                float od = __shfl_xor(ld, m, 64);
                int   oc = __shfl_xor(lc, m, 64);
                if (od < ld || (od == ld && oc < lc)) { ld = od; lc = oc; }
            }
            if (quad == 0) atomicMin(&runmin[nt * 16 + col], pack_dc(ld, lc));
        }
        // collect candidates below current runmin + TAU (superset invariant:
        // runmin only decreases, so thresholds are always >= final_min + TAU)
#pragma unroll
        for (int nt = 0; nt < 4; ++nt) {
            const int r = nt * 16 + col;
            const float thr = funkey(runmin[r] & 0xFFFFF800u) + TAU;
#pragma unroll
            for (int j = 0; j < 4; ++j) {
                if (dd[nt][j] < thr) {
                    unsigned slot = atomicAdd(&cnt[r], 1u);
                    if (slot < (unsigned)CAP)
                        cand[r * CAP + slot] = pack_dc(dd[nt][j], cb + wv * 16 + quad * 4 + j);
                }
            }
        }
    }
    __syncthreads();

    // ---- select: unambiguous rows decided by bf16; near-ties -> refine ----
    if (tid < ROWS) {
        const unsigned key = runmin[tid];
        const int   c1 = (int)(key & 0x7FFu);
        const float d1 = funkey(key & 0xFFFFF800u);
        const unsigned thr = ((fkey(d1 + SLACK)) & 0xFFFFF800u) | 0x7FFu;
        const int n = (int)min(cnt[tid], (unsigned)CAP);
        int m = 0; bool have_c1 = false;
        for (int t = 0; t < n; ++t) {
            unsigned e = cand[tid * CAP + t];
            if (e <= thr) {
                int code = (int)(e & 0x7FFu);
                if (code == c1) have_c1 = true;
                cand[tid * CAP + m++] = (unsigned)code;
            }
        }
        if (!have_c1 && m < CAP) cand[tid * CAP + m++] = (unsigned)c1;
        bestc[tid] = c1; dbest[tid] = d1;
        scnt[tid] = (m >= 2) ? m : 0;
    }
    __syncthreads();

    // ---- exact fp32 refinement (round-2 numerics), ~6% of rows ----
    for (int r = wv; r < ROWS; r += 4) {
        const int m = scnt[r];
        if (m == 0) continue;
        const size_t xb = (size_t)b * (DIM * HW) + hw0 + r;
        float xr0 = x[xb + (size_t)(4 * lane + 0) * HW];
        float xr1 = x[xb + (size_t)(4 * lane + 1) * HW];
        float xr2 = x[xb + (size_t)(4 * lane + 2) * HW];
        float xr3 = x[xb + (size_t)(4 * lane + 3) * HW];
        float bd = 1e38f; int bc = 0;
        for (int t = 0; t < m; ++t) {
            const int code = (int)cand[r * CAP + t];
            float4 wv4 = *reinterpret_cast<const float4*>(wg + (size_t)code * DIM + lane * 4);
            float sum = xr0 * wv4.x + xr1 * wv4.y + xr2 * wv4.z + xr3 * wv4.w;
#pragma unroll
            for (int o = 1; o < 64; o <<= 1) sum += __shfl_xor(sum, o, 64);
            float d = w2g[code] - 2.0f * sum;
            if (t == 0 || d < bd || (d == bd && code < bc)) { bd = d; bc = code; }
        }
        if (lane == 0) { bestc[r] = bc; dbest[r] = bd; }
    }
    __syncthreads();

    // ---- loss via identity: sum_r (d_best + ||x||^2) = sum (q-x)^2 ----
    if (tid == 0) {
        float ls = 0.f;
        for (int r = 0; r < ROWS; ++r) ls += dbest[r] + xn2[r];
        atomicAdd(loss_slot, ls * LOSS_SCALE);
    }

    // ---- epilogue: 4 passes x 16 rows; stage codewords fp32 -> coalesced out ----
    float* wst = (float*)ubuf;                    // [16][260]
    const int rl = tid >> 4;
    const int tt = tid & 15;
    for (int h = 0; h < 4; ++h) {
        __syncthreads();
        const float* wrow = wg + (size_t)bestc[h * 16 + rl] * DIM;
#pragma unroll
        for (int it = 0; it < 4; ++it) {
            const int c4 = it * 16 + tt;
            *reinterpret_cast<float4*>(wst + rl * 260 + c4 * 4) =
                *reinterpret_cast<const float4*>(wrow + c4 * 4);
        }
        __syncthreads();
#pragma unroll 4
        for (int it = 0; it < 16; ++it) {
            const int l = it * 256 + tid;
            const int i = l & 15, c = l >> 4;
            out[base + (size_t)c * HW + h * 16 + i] = wst[i * 260 + c];
        }
    }
}

extern "C" void kernel_launch(void* const* d_in, const int* in_sizes, int n_in,
                              void* d_out, int out_size, void* d_ws, size_t ws_size,
                              hipStream_t stream) {
    const float* x = (const float*)d_in[0];
    const float* w = (const float*)d_in[1];
    float* out       = (float*)d_out;
    float* loss_slot = out + NTOT;
    unsigned short* wbf = (unsigned short*)d_ws;   // 1 MB swizzled bf16 w
    float* w2 = (float*)((char*)d_ws + (size_t)NE * DIM * sizeof(unsigned short));

    prep_kernel<<<NE / 4, 256, 0, stream>>>(w, wbf, w2, loss_slot);
    vq_kernel<<<65536 / ROWS, 256, 0, stream>>>(x, w, wbf, w2, out, loss_slot);
}